// Round 11
// baseline (114.851 us; speedup 1.0000x reference)
//
#include <hip/hip_runtime.h>
#include <math.h>

#define BB   4
#define HH   96
#define WW   96
#define HW   (HH * WW)          // 9216
#define CIN  64
#define COUT 64
#define NPL  17                 // activation planes: fi 0-7, fj(phys) 8-15, flow 16
#define HWP  (HW + 1)           // uint4 per plane: HW positions + zero slot at HW
#define NROW (BB * HW)          // 36864
#define MPB  32                 // positions per fused block (third of a row)
#define NBLK (NROW / MPB)       // 1152 fused blocks
#define BPX4 (NBLK / 8)         // 144 fused blocks per XCD slice
#define NA   (9 * 5 * 2 * 512)  // wa2f elements (46080), fragment-dense
#define NW   (9 * 2 * 4 * 512)  // wb2f elements (36864), fragment-dense
#define PXB2 (NROW / 32)        // 1152 prep X-blocks (64 rows, half channels)
#define PWBLK 324               // weight blocks covering NA+NW elements
#define TSX  35                 // prep LDS tile stride (dwords), conflict-free
#define NIT2 (NPL * 102)        // 1734 staging items (17 planes x 3 runs x 34)

typedef short v8s __attribute__((ext_vector_type(8)));   // 8 bf16 = 4 VGPRs
typedef float v4f __attribute__((ext_vector_type(4)));

__device__ __forceinline__ unsigned short f2bf(float f) {
    unsigned u = __float_as_uint(f);
    return (unsigned short)((u + 0x7FFFu + ((u >> 16) & 1u)) >> 16);  // RTN-even
}
__device__ __forceinline__ unsigned pack2(float a, float b) {
    return (unsigned)f2bf(a) | ((unsigned)f2bf(b) << 16);
}
__device__ __forceinline__ unsigned bil2(unsigned a, unsigned b, unsigned c,
                                         unsigned d, float w00, float w01,
                                         float w10, float w11) {
    float lo = w00 * __uint_as_float(a << 16) + w01 * __uint_as_float(b << 16)
             + w10 * __uint_as_float(c << 16) + w11 * __uint_as_float(d << 16);
    float hi = w00 * __uint_as_float(a & 0xffff0000u)
             + w01 * __uint_as_float(b & 0xffff0000u)
             + w10 * __uint_as_float(c & 0xffff0000u)
             + w11 * __uint_as_float(d & 0xffff0000u);
    return pack2(lo, hi);
}

// ---------------------------------------------------------------------------
// Prep (unchanged from R10, known-good). Plane-major xp[b][pl][HWP]:
// fi planes 0-7, fj PHYS planes 8-15 (pl holds orig chunk (pl>>1)+(pl&1)*4),
// flow plane 16; index HW of each plane is a zero slot.
// ---------------------------------------------------------------------------
__global__ __launch_bounds__(256) void prep_kernel(
    const float* __restrict__ fi, const float* __restrict__ fj,
    const float* __restrict__ fl, const float* __restrict__ w_off,
    const float* __restrict__ w_mod, const float* __restrict__ w_reg,
    uint4* __restrict__ xp, unsigned short* __restrict__ wa2f,
    unsigned short* __restrict__ wb2f)
{
    int blk = blockIdx.x;
    if (blk < PXB2) {
        __shared__ __align__(16) unsigned tile[64 * TSX];  // 9 KB
        int tid = threadIdx.x;
        int p = tid & 63, cg = tid >> 6;    // position, channel-group 0..3
        int u = blk >> 1, half = blk & 1;
        int r0 = u * 64;
        int b = r0 / HW;                    // 64-row strip never straddles b
        int hwb = r0 - b * HW;              // strip base within image
        int hw = hwb + p;
        uint4* xpb = xp + (size_t)b * NPL * HWP;
        if (half == 0) {                    // fi -> planes 0..7
            const float* pi = fi + (size_t)b * CIN * HW + hw;
#pragma unroll
            for (int d = 0; d < 8; ++d) {
                int c = cg * 16 + 2 * d;
                tile[p * TSX + cg * 8 + d] =
                    pack2(pi[(size_t)c * HW], pi[(size_t)(c + 1) * HW]);
            }
            __syncthreads();
#pragma unroll
            for (int i = 0; i < 2; ++i) {   // 512 plane-stores, coalesced
                int it = i * 256 + tid;
                int pl = it >> 6, rl = it & 63;
                const unsigned* s = &tile[rl * TSX + pl * 4];
                uint4 v = {s[0], s[1], s[2], s[3]};
                xpb[(size_t)pl * HWP + hwb + rl] = v;
            }
        } else {                            // fj(phys planes) + flow -> 8..16
            const float* pj = fj + (size_t)b * CIN * HW + hw;
#pragma unroll
            for (int d = 0; d < 8; ++d) {
                int c = cg * 16 + 2 * d;
                tile[p * TSX + cg * 8 + d] =
                    pack2(pj[(size_t)c * HW], pj[(size_t)(c + 1) * HW]);
            }
            if (cg == 0) {
                const float* pf = fl + (size_t)b * 2 * HW + hw;
                tile[p * TSX + 32] = pack2(pf[0], pf[HW]);
            }
            __syncthreads();
#pragma unroll
            for (int i = 0; i < 2; ++i) {   // 512 fj plane-stores (permuted)
                int it = i * 256 + tid;
                int pl = it >> 6, rl = it & 63;        // phys plane 0..7
                int o  = (pl >> 1) + (pl & 1) * 4;     // orig chunk
                const unsigned* s = &tile[rl * TSX + o * 4];
                uint4 v = {s[0], s[1], s[2], s[3]};
                xpb[(size_t)(8 + pl) * HWP + hwb + rl] = v;
            }
            if (tid < 64) {                 // flow plane 16
                uint4 v = {tile[tid * TSX + 32], 0u, 0u, 0u};
                xpb[(size_t)16 * HWP + hwb + tid] = v;
            }
        }
    } else if (blk < PXB2 + PWBLK) {
        int e = (blk - PXB2) * 256 + threadIdx.x;
        if (e < NA) {                       // wa2f, fragment-dense
            int t  = e / 5120;
            int r1 = e - t * 5120;
            int ks = r1 >> 10;
            int r2 = r1 & 1023;
            int nt = r2 >> 9;
            int l9 = r2 & 511;
            int l  = l9 >> 3, ee = l9 & 7;
            int m  = l & 15, g = l >> 4;
            int oc = nt * 16 + m;
            int ch = ks * 32 + g * 8 + ee;
            float v = 0.0f;
            if (oc < 27 && ch < 130) {
                if (oc < 18) v = w_off[((size_t)oc * 130 + ch) * 9 + t];
                else         v = w_mod[((size_t)(oc - 18) * 130 + ch) * 9 + t];
            }
            wa2f[e] = f2bf(v);
        } else {
            int e2 = e - NA;
            if (e2 < NW) {                  // wb2f, fragment-dense
                int k  = e2 >> 12;
                int r1 = e2 & 4095;
                int ks = r1 >> 11;
                int r2 = r1 & 2047;
                int nt = r2 >> 9;
                int l9 = r2 & 511;
                int l  = l9 >> 3, ee = l9 & 7;
                int m  = l & 15, g = l >> 4;
                int o  = nt * 16 + m;
                int c  = ks * 32 + g * 8 + ee;
                wb2f[e2] = f2bf(w_reg[((size_t)o * 64 + c) * 9 + k]);
            }
        }
    } else {
        if (threadIdx.x < BB * NPL) {       // 68 zero slots (index HW per plane)
            int bz = threadIdx.x / NPL, pl = threadIdx.x - bz * NPL;
            uint4 z = {0u, 0u, 0u, 0u};
            xp[((size_t)bz * NPL + pl) * HWP + HW] = z;
        }
    }
}

// ---------------------------------------------------------------------------
// Fused conv + deform. R25: M=32 positions/block (weight amortization, the
// L2-traffic round). Each wave loads each B-fragment ONCE and feeds two
// A-subtiles (q=0: pos 0-15, q=1: pos 16-31). L2 bytes/block: weights 158 KB
// (now amortized over 32 pos), staging 27.7 KB, gathers ~148 KB -> total
// traffic drops ~33% vs R10. Two-stage reductions in BOTH phases keep LDS at
// 52.7 KB (pool 32 KB = patch 27.7 / red2 32; red1 16 KB; lraw 3.6 KB)
// -> 3 blocks/CU by LDS. __launch_bounds__(512,4): R4-proven, no spills.
// ---------------------------------------------------------------------------
__global__ __launch_bounds__(512, 4) void fused_kernel(
    const uint4* __restrict__ xp,
    const unsigned short* __restrict__ wa2f,
    const unsigned short* __restrict__ wb2f,
    const float* __restrict__ b_off, const float* __restrict__ b_mod,
    float* __restrict__ out)
{
    // pool: [0,27744) patchL (stage..barrier A1) | [0,32768) red2 (after B)
    __shared__ __align__(16) unsigned char pool[32768];
    __shared__ __align__(16) float red1[4][16][64];   // 16 KB ph1 partials
    __shared__ float lraw[32 * 28];                   // 3.6 KB offsets/mods

    uint4* patchL = (uint4*)pool;
    float* red2   = (float*)pool;                     // [4][32][64]

    int tid = threadIdx.x;
    int l = tid & 63;
    int wid = __builtin_amdgcn_readfirstlane(tid >> 6);  // 0..7
    int m = l & 15, g = l >> 4;
    int blkid = (blockIdx.x & 7) * BPX4 + (blockIdx.x >> 3);  // XCD-contiguous
    int b = blkid / (HW / MPB);             // wave-uniform
    int rem = blkid - b * (HW / MPB);       // 0..287
    int y = rem / 3;                        // row
    int x0b = (rem - y * 3) * 32;           // 0 / 32 / 64
    int hw0 = y * WW + x0b;

    const uint4* xpb = xp + (size_t)b * NPL * HWP;

    // ---- Stage 1734 items: plane-major, contiguous runs of 34 slots ----
#pragma unroll
    for (int i = 0; i < 4; ++i) {
        int item = i * 512 + tid;
        if (item < NIT2) {
            int pl  = item / 102;
            int rm  = item - pl * 102;
            int run = rm / 34;
            int c34 = rm - run * 34;
            int yy = y + run - 1;
            int xx = x0b - 1 + c34;
            bool ok = ((unsigned)yy < HH) && ((unsigned)xx < WW);
            int pos = ok ? (yy * WW + xx) : HW;     // HW = zero slot
            patchL[item] = xpb[(size_t)pl * HWP + pos];
        }
    }
    __syncthreads();                        // barrier S

    // ---- Phase 1: 45 (t,ks) units over 8 waves; each unit hits q=0 AND q=1
    v4f acc00 = {0.f, 0.f, 0.f, 0.f};      // q0, channels 0-15
    v4f acc01 = {0.f, 0.f, 0.f, 0.f};      // q0, channels 16-31
    v4f acc10 = {0.f, 0.f, 0.f, 0.f};      // q1, channels 0-15
    v4f acc11 = {0.f, 0.f, 0.f, 0.f};      // q1, channels 16-31
    {
        int nu = (wid < 5) ? 6 : 5;         // wave-uniform unit count
#pragma unroll
        for (int i = 0; i < 6; ++i) {
            if (i < nu) {
                int u = wid + 8 * i;        // unit = t*5+ks, uniform
                int t = u / 5, ks = u - 5 * t;
                int run = t / 3, kx = t - 3 * run;
                int rb = run * 34 + kx + m;
                v8s a0, a1;
                if (ks == 4) {              // flow plane; zero for g>0
                    uint4 t0 = patchL[16 * 102 + rb];
                    uint4 t1 = patchL[16 * 102 + rb + 16];
                    if (g) { t0 = (uint4){0u,0u,0u,0u}; t1 = (uint4){0u,0u,0u,0u}; }
                    a0 = __builtin_bit_cast(v8s, t0);
                    a1 = __builtin_bit_cast(v8s, t1);
                } else {
                    int pl = (ks == 0) ? g : (ks == 1) ? 4 + g
                           : (ks == 2) ? 8 + 2 * g : 9 + 2 * g;
                    a0 = *(const v8s*)&patchL[pl * 102 + rb];
                    a1 = *(const v8s*)&patchL[pl * 102 + rb + 16];
                }
                const unsigned short* wp =
                    wa2f + ((size_t)(u * 2)) * 512 + l * 8;
                v8s b0 = *(const v8s*)(wp);
                v8s b1 = *(const v8s*)(wp + 512);
                acc00 = __builtin_amdgcn_mfma_f32_16x16x32_bf16(a0, b0, acc00, 0, 0, 0);
                acc01 = __builtin_amdgcn_mfma_f32_16x16x32_bf16(a0, b1, acc01, 0, 0, 0);
                acc10 = __builtin_amdgcn_mfma_f32_16x16x32_bf16(a1, b0, acc10, 0, 0, 0);
                acc11 = __builtin_amdgcn_mfma_f32_16x16x32_bf16(a1, b1, acc11, 0, 0, 0);
            }
        }
    }

    // ---- ph1 two-stage reduction: red1 = 4 buffers x 16 slots ----
    if (wid >= 4) {                         // stage A: waves 4-7 publish
        float* rb = &red1[wid - 4][0][0];
#pragma unroll
        for (int j = 0; j < 4; ++j) {
            rb[(0 + j) * 64 + l]  = acc00[j];       // s = 0*8 + j
            rb[(4 + j) * 64 + l]  = acc01[j];       // s = 0*8 + 4+j
            rb[(8 + j) * 64 + l]  = acc10[j];       // s = 1*8 + j
            rb[(12 + j) * 64 + l] = acc11[j];       // s = 1*8 + 4+j
        }
    }
    __syncthreads();                        // barrier A1 (patchL still live? no:
                                            // ph1 reads done pre-publish)
    if (wid < 4) {                          // stage B: waves 0-3 add in place
        float* rb = &red1[wid][0][0];
#pragma unroll
        for (int j = 0; j < 4; ++j) {
            rb[(0 + j) * 64 + l]  += acc00[j];
            rb[(4 + j) * 64 + l]  += acc01[j];
            rb[(8 + j) * 64 + l]  += acc10[j];
            rb[(12 + j) * 64 + l] += acc11[j];
        }
    }
    __syncthreads();                        // barrier A2

    {   // reduce + epilogue: wave w owns slots s = 2w, 2w+1 (s = q*8 + j)
#pragma unroll
        for (int ss = 0; ss < 2; ++ss) {
            int s = wid * 2 + ss;
            int q = s >> 3, j = s & 7;
            float v = red1[0][s][l] + red1[1][s][l]
                    + red1[2][s][l] + red1[3][s][l];
            int r = j & 3;
            int oc = (j < 4) ? m : 16 + m;
            int pos = q * 16 + g * 4 + r;
            if (oc < 18) {
                lraw[pos * 28 + oc] = v + b_off[oc];
            } else if (oc < 27) {
                lraw[pos * 28 + oc] =
                    2.0f / (1.0f + __expf(-(v + b_mod[oc - 18])));
            }
        }
    }
    __syncthreads();                        // barrier B (red1 dead, red2 born)

    // ---- Phase 2: wave w owns tap w for BOTH q; tap 8 split to waves 6/7 ----
    v4f acc2[2][4];
#pragma unroll
    for (int q = 0; q < 2; ++q)
#pragma unroll
        for (int nt = 0; nt < 4; ++nt) acc2[q][nt] = (v4f){0.f, 0.f, 0.f, 0.f};

    const uint4* p0 = xpb + (size_t)(8 + 2 * g) * HWP;
    const uint4* p1 = p0 + HWP;

    // gather + bilinear for (tap k, subtile q, plane-half ks or both)
    auto mk_af = [&](int k, int q, v8s& af0, v8s& af1) {
        int ky = k / 3, kx = k - 3 * ky;
        int pos = q * 16 + m;
        float dy = lraw[pos * 28 + 2 * k];
        float dx = lraw[pos * 28 + 2 * k + 1];
        float mm = lraw[pos * 28 + 18 + k];

        float py = (float)(y - 1 + ky) + dy;
        float px = (float)(x0b + pos - 1 + kx) + dx;
        float fy = floorf(py), fx = floorf(px);
        int   y0 = (int)fy,    x0 = (int)fx;
        float wy = py - fy,    wx = px - fx;
        int   y1 = y0 + 1,     x1 = x0 + 1;

        bool y0v = (y0 >= 0) && (y0 < HH);
        bool y1v = (y1 >= 0) && (y1 < HH);
        bool x0v = (x0 >= 0) && (x0 < WW);
        bool x1v = (x1 >= 0) && (x1 < WW);

        float w00 = (1.f - wy) * (1.f - wx) * ((y0v && x0v) ? mm : 0.f);
        float w01 = (1.f - wy) * wx         * ((y0v && x1v) ? mm : 0.f);
        float w10 = wy * (1.f - wx)         * ((y1v && x0v) ? mm : 0.f);
        float w11 = wy * wx                 * ((y1v && x1v) ? mm : 0.f);

        int y0c = min(max(y0, 0), HH - 1), y1c = min(max(y1, 0), HH - 1);
        int x0c = min(max(x0, 0), WW - 1), x1c = min(max(x1, 0), WW - 1);
        int i00 = y0c * WW + x0c, i01 = y0c * WW + x1c;
        int i10 = y1c * WW + x0c, i11 = y1c * WW + x1c;

        uint4 a00 = p0[i00];
        uint4 a01 = p0[i01];
        uint4 a10 = p0[i10];
        uint4 a11 = p0[i11];
        uint4 c00 = p1[i00];
        uint4 c01 = p1[i01];
        uint4 c10 = p1[i10];
        uint4 c11 = p1[i11];

        uint4 ov0, ov1;
        ov0.x = bil2(a00.x, a01.x, a10.x, a11.x, w00, w01, w10, w11);
        ov0.y = bil2(a00.y, a01.y, a10.y, a11.y, w00, w01, w10, w11);
        ov0.z = bil2(a00.z, a01.z, a10.z, a11.z, w00, w01, w10, w11);
        ov0.w = bil2(a00.w, a01.w, a10.w, a11.w, w00, w01, w10, w11);
        ov1.x = bil2(c00.x, c01.x, c10.x, c11.x, w00, w01, w10, w11);
        ov1.y = bil2(c00.y, c01.y, c10.y, c11.y, w00, w01, w10, w11);
        ov1.z = bil2(c00.z, c01.z, c10.z, c11.z, w00, w01, w10, w11);
        ov1.w = bil2(c00.w, c01.w, c10.w, c11.w, w00, w01, w10, w11);
        af0 = __builtin_bit_cast(v8s, ov0);
        af1 = __builtin_bit_cast(v8s, ov1);
    };

    auto do_tap = [&](int k) {
        v8s af[2][2];                       // [q][ks]
        mk_af(k, 0, af[0][0], af[0][1]);
        mk_af(k, 1, af[1][0], af[1][1]);
        // weights loaded ONCE, feed both q
#pragma unroll
        for (int nt = 0; nt < 4; ++nt) {
            const unsigned short* wp0 =
                wb2f + ((size_t)((k * 2 + 0) * 4 + nt)) * 512 + l * 8;
            const unsigned short* wp1 =
                wb2f + ((size_t)((k * 2 + 1) * 4 + nt)) * 512 + l * 8;
            v8s bb0 = *(const v8s*)wp0;
            v8s bb1 = *(const v8s*)wp1;
            acc2[0][nt] = __builtin_amdgcn_mfma_f32_16x16x32_bf16(af[0][0], bb0, acc2[0][nt], 0, 0, 0);
            acc2[0][nt] = __builtin_amdgcn_mfma_f32_16x16x32_bf16(af[0][1], bb1, acc2[0][nt], 0, 0, 0);
            acc2[1][nt] = __builtin_amdgcn_mfma_f32_16x16x32_bf16(af[1][0], bb0, acc2[1][nt], 0, 0, 0);
            acc2[1][nt] = __builtin_amdgcn_mfma_f32_16x16x32_bf16(af[1][1], bb1, acc2[1][nt], 0, 0, 0);
        }
    };

    // half-tap (one ks plane) for the tap-8 split
    auto do_half = [&](int k, int ks) {
        v8s af[2];                          // [q]
#pragma unroll
        for (int q = 0; q < 2; ++q) {
            int ky = k / 3, kx = k - 3 * ky;
            int pos = q * 16 + m;
            float dy = lraw[pos * 28 + 2 * k];
            float dx = lraw[pos * 28 + 2 * k + 1];
            float mm = lraw[pos * 28 + 18 + k];

            float py = (float)(y - 1 + ky) + dy;
            float px = (float)(x0b + pos - 1 + kx) + dx;
            float fy = floorf(py), fx = floorf(px);
            int   y0 = (int)fy,    x0 = (int)fx;
            float wy = py - fy,    wx = px - fx;
            int   y1 = y0 + 1,     x1 = x0 + 1;

            bool y0v = (y0 >= 0) && (y0 < HH);
            bool y1v = (y1 >= 0) && (y1 < HH);
            bool x0v = (x0 >= 0) && (x0 < WW);
            bool x1v = (x1 >= 0) && (x1 < WW);

            float w00 = (1.f - wy) * (1.f - wx) * ((y0v && x0v) ? mm : 0.f);
            float w01 = (1.f - wy) * wx         * ((y0v && x1v) ? mm : 0.f);
            float w10 = wy * (1.f - wx)         * ((y1v && x0v) ? mm : 0.f);
            float w11 = wy * wx                 * ((y1v && x1v) ? mm : 0.f);

            int y0c = min(max(y0, 0), HH - 1), y1c = min(max(y1, 0), HH - 1);
            int x0c = min(max(x0, 0), WW - 1), x1c = min(max(x1, 0), WW - 1);
            int i00 = y0c * WW + x0c, i01 = y0c * WW + x1c;
            int i10 = y1c * WW + x0c, i11 = y1c * WW + x1c;

            const uint4* pk = xpb + (size_t)(8 + 2 * g + ks) * HWP;
            uint4 a00 = pk[i00];
            uint4 a01 = pk[i01];
            uint4 a10 = pk[i10];
            uint4 a11 = pk[i11];

            uint4 ov;
            ov.x = bil2(a00.x, a01.x, a10.x, a11.x, w00, w01, w10, w11);
            ov.y = bil2(a00.y, a01.y, a10.y, a11.y, w00, w01, w10, w11);
            ov.z = bil2(a00.z, a01.z, a10.z, a11.z, w00, w01, w10, w11);
            ov.w = bil2(a00.w, a01.w, a10.w, a11.w, w00, w01, w10, w11);
            af[q] = __builtin_bit_cast(v8s, ov);
        }
#pragma unroll
        for (int nt = 0; nt < 4; ++nt) {
            const unsigned short* wp =
                wb2f + ((size_t)((k * 2 + ks) * 4 + nt)) * 512 + l * 8;
            v8s bb = *(const v8s*)wp;
            acc2[0][nt] = __builtin_amdgcn_mfma_f32_16x16x32_bf16(af[0], bb, acc2[0][nt], 0, 0, 0);
            acc2[1][nt] = __builtin_amdgcn_mfma_f32_16x16x32_bf16(af[1], bb, acc2[1][nt], 0, 0, 0);
        }
    };

    do_tap(wid);
    if (wid == 6) do_half(8, 0);
    if (wid == 7) do_half(8, 1);

    __syncthreads();                        // barrier C0 (lraw reads done;
                                            // red2 may now overwrite pool)
    // ---- ph2 two-stage reduction: red2 = 4 buffers x 32 slots (32 KB) ----
    if (wid >= 4) {                         // stage A: waves 4-7 publish
        float* rb = red2 + ((size_t)(wid - 4) * 32) * 64;
#pragma unroll
        for (int q = 0; q < 2; ++q)
#pragma unroll
            for (int nt = 0; nt < 4; ++nt)
#pragma unroll
                for (int r = 0; r < 4; ++r)
                    rb[(q * 16 + nt * 4 + r) * 64 + l] = acc2[q][nt][r];
    }
    __syncthreads();                        // barrier C1
    if (wid < 4) {                          // stage B: waves 0-3 add in place
        float* rb = red2 + ((size_t)wid * 32) * 64;
#pragma unroll
        for (int q = 0; q < 2; ++q)
#pragma unroll
            for (int nt = 0; nt < 4; ++nt)
#pragma unroll
                for (int r = 0; r < 4; ++r) {
                    float t = rb[(q * 16 + nt * 4 + r) * 64 + l] + acc2[q][nt][r];
                    rb[(q * 16 + nt * 4 + r) * 64 + l] = t;
                }
    }
    __syncthreads();                        // barrier C2
    {   // stage C: wave w owns (q,nt) = (w>>2, w&3): 4 consecutive r slots
        int q = wid >> 2, nt = wid & 3;
        v4f s = {0.f, 0.f, 0.f, 0.f};
#pragma unroll
        for (int r = 0; r < 4; ++r) {
            float t = 0.f;
#pragma unroll
            for (int bu = 0; bu < 4; ++bu)
                t += red2[((size_t)bu * 32 + q * 16 + nt * 4 + r) * 64 + l];
            s[r] = t;
        }
        float* op = out + ((size_t)(b * COUT + nt * 16 + m)) * HW
                  + hw0 + q * 16 + g * 4;
        *(v4f*)op = s;
    }
}

extern "C" void kernel_launch(void* const* d_in, const int* in_sizes, int n_in,
                              void* d_out, int out_size, void* d_ws, size_t ws_size,
                              hipStream_t stream)
{
    const float* frame_i = (const float*)d_in[0];
    const float* frame_j = (const float*)d_in[1];
    const float* flow_ij = (const float*)d_in[2];
    const float* w_off   = (const float*)d_in[3];
    const float* b_off   = (const float*)d_in[4];
    const float* w_mod   = (const float*)d_in[5];
    const float* b_mod   = (const float*)d_in[6];
    const float* w_reg   = (const float*)d_in[7];
    float* out = (float*)d_out;

    // workspace: xp uint4[BB*NPL*HWP] (~10 MB) | Wa2f | Wb2f
    uint4* xp = (uint4*)d_ws;
    unsigned short* wa2f = (unsigned short*)(xp + (size_t)BB * NPL * HWP);
    unsigned short* wb2f = wa2f + NA;

    prep_kernel<<<PXB2 + PWBLK + 1, 256, 0, stream>>>(
        frame_i, frame_j, flow_ij, w_off, w_mod, w_reg, xp, wa2f, wb2f);

    fused_kernel<<<NBLK, 512, 0, stream>>>(
        xp, wa2f, wb2f, b_off, b_mod, out);
}

// Round 12
// 113.771 us; speedup vs baseline: 1.0095x; 1.0095x over previous
//
#include <hip/hip_runtime.h>
#include <math.h>

#define BB   4
#define HH   96
#define WW   96
#define HW   (HH * WW)          // 9216
#define CIN  64
#define COUT 64
#define NPL  17                 // activation planes: fi 0-7, fj(phys) 8-15, flow 16
#define HWP  (HW + 1)           // uint4 per plane: HW positions + zero slot at HW
#define NROW (BB * HW)          // 36864
#define NSTRIP (NROW / 16)      // 2304 strips of 16 positions
#define BPX3 (NSTRIP / 8)       // 288 strips per XCD slice
#define NA   (9 * 5 * 2 * 512)  // wa2f elements (46080), fragment-dense
#define NW   (9 * 2 * 4 * 512)  // wb2f elements (36864), fragment-dense
#define PXB3 ((NROW / 128) * 2) // 576 prep X-blocks (128 pos, half channels)
#define PWBLK 324               // weight blocks covering NA+NW elements
#define TSX  35                 // prep LDS tile stride (dwords), conflict-free
#define NIT  (NPL * 54)         // 918 staging items (17 planes x 54 positions)

typedef short v8s __attribute__((ext_vector_type(8)));   // 8 bf16 = 4 VGPRs
typedef float v4f __attribute__((ext_vector_type(4)));

__device__ __forceinline__ unsigned short f2bf(float f) {
    unsigned u = __float_as_uint(f);
    return (unsigned short)((u + 0x7FFFu + ((u >> 16) & 1u)) >> 16);  // RTN-even
}
__device__ __forceinline__ unsigned pack2(float a, float b) {
    return (unsigned)f2bf(a) | ((unsigned)f2bf(b) << 16);
}
__device__ __forceinline__ unsigned bil2(unsigned a, unsigned b, unsigned c,
                                         unsigned d, float w00, float w01,
                                         float w10, float w11) {
    float lo = w00 * __uint_as_float(a << 16) + w01 * __uint_as_float(b << 16)
             + w10 * __uint_as_float(c << 16) + w11 * __uint_as_float(d << 16);
    float hi = w00 * __uint_as_float(a & 0xffff0000u)
             + w01 * __uint_as_float(b & 0xffff0000u)
             + w10 * __uint_as_float(c & 0xffff0000u)
             + w11 * __uint_as_float(d & 0xffff0000u);
    return pack2(lo, hi);
}

// ---------------------------------------------------------------------------
// Prep R26: X-blocks cover 128 positions with FLOAT2 input loads (positions
// 2p/2p+1 share one 8-B load per channel row) — 16 float2 loads per thread
// instead of 32 scalar loads; X-block count halves (1152 -> 576). LDS tile
// 128 x TSX dwords (17.9 KB); write (6p+col)%32 and read (3rl+c)%32 are both
// 2-way bank aliases (free). Output layout xp[b][pl][HWP] unchanged from R10.
// ---------------------------------------------------------------------------
__global__ __launch_bounds__(256) void prep_kernel(
    const float* __restrict__ fi, const float* __restrict__ fj,
    const float* __restrict__ fl, const float* __restrict__ w_off,
    const float* __restrict__ w_mod, const float* __restrict__ w_reg,
    uint4* __restrict__ xp, unsigned short* __restrict__ wa2f,
    unsigned short* __restrict__ wb2f)
{
    int blk = blockIdx.x;
    if (blk < PXB3) {
        __shared__ __align__(16) unsigned tile[128 * TSX];  // 17.9 KB
        int tid = threadIdx.x;
        int p = tid & 63, cg = tid >> 6;    // position-pair, channel-group 0..3
        int u = blk >> 1, half = blk & 1;
        int r0 = u * 128;                   // 9216 % 128 == 0: never straddles b
        int b = r0 / HW;
        int hwb = r0 - b * HW;              // strip base within image
        int hw2 = hwb + 2 * p;              // this thread's position pair
        uint4* xpb = xp + (size_t)b * NPL * HWP;
        if (half == 0) {                    // fi -> planes 0..7
            const float* pi = fi + (size_t)b * CIN * HW + hw2;
#pragma unroll
            for (int d = 0; d < 8; ++d) {
                int c = cg * 16 + 2 * d;
                float2 v0 = *(const float2*)&pi[(size_t)c * HW];
                float2 v1 = *(const float2*)&pi[(size_t)(c + 1) * HW];
                tile[(2 * p) * TSX + cg * 8 + d]     = pack2(v0.x, v1.x);
                tile[(2 * p + 1) * TSX + cg * 8 + d] = pack2(v0.y, v1.y);
            }
            __syncthreads();
#pragma unroll
            for (int i = 0; i < 4; ++i) {   // 1024 uint4 plane-stores
                int it = i * 256 + tid;
                int pl = it >> 7, rl = it & 127;
                const unsigned* s = &tile[rl * TSX + pl * 4];
                uint4 v = {s[0], s[1], s[2], s[3]};
                xpb[(size_t)pl * HWP + hwb + rl] = v;
            }
        } else {                            // fj(phys planes) + flow -> 8..16
            const float* pj = fj + (size_t)b * CIN * HW + hw2;
#pragma unroll
            for (int d = 0; d < 8; ++d) {
                int c = cg * 16 + 2 * d;
                float2 v0 = *(const float2*)&pj[(size_t)c * HW];
                float2 v1 = *(const float2*)&pj[(size_t)(c + 1) * HW];
                tile[(2 * p) * TSX + cg * 8 + d]     = pack2(v0.x, v1.x);
                tile[(2 * p + 1) * TSX + cg * 8 + d] = pack2(v0.y, v1.y);
            }
            if (cg == 0) {                  // flow: 2 positions per thread
                const float* pf = fl + (size_t)b * 2 * HW + hw2;
                float2 f0 = *(const float2*)&pf[0];
                float2 f1 = *(const float2*)&pf[HW];
                tile[(2 * p) * TSX + 32]     = pack2(f0.x, f1.x);
                tile[(2 * p + 1) * TSX + 32] = pack2(f0.y, f1.y);
            }
            __syncthreads();
#pragma unroll
            for (int i = 0; i < 4; ++i) {   // 1024 fj plane-stores (permuted)
                int it = i * 256 + tid;
                int pl = it >> 7, rl = it & 127;       // phys plane 0..7
                int o  = (pl >> 1) + (pl & 1) * 4;     // orig chunk
                const unsigned* s = &tile[rl * TSX + o * 4];
                uint4 v = {s[0], s[1], s[2], s[3]};
                xpb[(size_t)(8 + pl) * HWP + hwb + rl] = v;
            }
            if (tid < 128) {                // flow plane 16
                uint4 v = {tile[tid * TSX + 32], 0u, 0u, 0u};
                xpb[(size_t)16 * HWP + hwb + tid] = v;
            }
        }
    } else if (blk < PXB3 + PWBLK) {
        int e = (blk - PXB3) * 256 + threadIdx.x;
        if (e < NA) {                       // wa2f, fragment-dense
            int t  = e / 5120;
            int r1 = e - t * 5120;
            int ks = r1 >> 10;
            int r2 = r1 & 1023;
            int nt = r2 >> 9;
            int l9 = r2 & 511;
            int l  = l9 >> 3, ee = l9 & 7;
            int m  = l & 15, g = l >> 4;
            int oc = nt * 16 + m;
            int ch = ks * 32 + g * 8 + ee;
            float v = 0.0f;
            if (oc < 27 && ch < 130) {
                if (oc < 18) v = w_off[((size_t)oc * 130 + ch) * 9 + t];
                else         v = w_mod[((size_t)(oc - 18) * 130 + ch) * 9 + t];
            }
            wa2f[e] = f2bf(v);
        } else {
            int e2 = e - NA;
            if (e2 < NW) {                  // wb2f, fragment-dense
                int k  = e2 >> 12;
                int r1 = e2 & 4095;
                int ks = r1 >> 11;
                int r2 = r1 & 2047;
                int nt = r2 >> 9;
                int l9 = r2 & 511;
                int l  = l9 >> 3, ee = l9 & 7;
                int m  = l & 15, g = l >> 4;
                int o  = nt * 16 + m;
                int c  = ks * 32 + g * 8 + ee;
                wb2f[e2] = f2bf(w_reg[((size_t)o * 64 + c) * 9 + k]);
            }
        }
    } else {
        if (threadIdx.x < BB * NPL) {       // 68 zero slots (index HW per plane)
            int bz = threadIdx.x / NPL, pl = threadIdx.x - bz * NPL;
            uint4 z = {0u, 0u, 0u, 0u};
            xp[((size_t)bz * NPL + pl) * HWP + HW] = z;
        }
    }
}

// ---------------------------------------------------------------------------
// Fused conv + deform. Byte-identical to R10/R24 (best verified: 112.1 us).
// ---------------------------------------------------------------------------
__global__ __launch_bounds__(512, 8) void fused_kernel(
    const uint4* __restrict__ xp,
    const unsigned short* __restrict__ wa2f,
    const unsigned short* __restrict__ wb2f,
    const float* __restrict__ b_off, const float* __restrict__ b_mod,
    float* __restrict__ out)
{
    // pool: [0,14688) patchL (stage..barrier A) | [0,16384) red2 (after B)
    __shared__ __align__(16) unsigned char pool[16384];
    __shared__ __align__(16) float red1[8][8][64];    // 16 KB ph1 partials
    __shared__ float lraw[16 * 28];                   // 1.8 KB offsets/mods

    uint4* patchL = (uint4*)pool;
    float* red2   = (float*)pool;                     // [4][16][64]

    int tid = threadIdx.x;
    int l = tid & 63;
    int wid = __builtin_amdgcn_readfirstlane(tid >> 6);  // 0..7
    int m = l & 15, g = l >> 4;
    int strip = (blockIdx.x & 7) * BPX3 + (blockIdx.x >> 3);  // XCD-contiguous
    int b = strip / (HW / 16);              // wave-uniform
    int hw0 = (strip - b * (HW / 16)) * 16;
    int hw = hw0 + m;
    int x = hw % WW, y = hw / WW;
    int y0b = hw0 / WW, x0b = hw0 - y0b * WW;   // strip base (x0b mult of 16)

    const uint4* xpb = xp + (size_t)b * NPL * HWP;

    // ---- Stage 918 items: plane-major, contiguous 288-B runs ----
#pragma unroll
    for (int i = 0; i < 2; ++i) {
        int item = i * 512 + tid;
        if (item < NIT) {
            int pl  = item / 54;
            int rm  = item - pl * 54;
            int run = rm / 18;
            int r18 = rm - run * 18;
            int yy = y0b + run - 1;
            int xx = x0b - 1 + r18;
            bool ok = ((unsigned)yy < HH) && ((unsigned)xx < WW);
            int pos = ok ? (yy * WW + xx) : HW;     // HW = zero slot
            patchL[item] = xpb[(size_t)pl * HWP + pos];
        }
    }
    __syncthreads();                        // barrier S

    // ---- Phase 1: conv partials, 45 units over 8 waves (6/6/6/6/6/5/5/5) ----
    v4f acc0 = {0.f, 0.f, 0.f, 0.f};
    v4f acc1 = {0.f, 0.f, 0.f, 0.f};
    {
        int nu = (wid < 5) ? 6 : 5;         // wave-uniform unit count
#pragma unroll
        for (int i = 0; i < 6; ++i) {
            if (i < nu) {
                int u = wid + 8 * i;        // unit = t*5+ks, uniform
                int t = u / 5, ks = u - 5 * t;
                int r = (t / 3) * 18 + (t % 3) + m;
                v8s a;
                if (ks == 4) {              // flow plane; zero for g>0
                    uint4 t4 = patchL[16 * 54 + r];  // broadcast across g
                    if (g) t4 = (uint4){0u, 0u, 0u, 0u};
                    a = __builtin_bit_cast(v8s, t4);
                } else {
                    int pl = (ks == 0) ? g : (ks == 1) ? 4 + g
                           : (ks == 2) ? 8 + 2 * g : 9 + 2 * g;
                    a = *(const v8s*)&patchL[pl * 54 + r];
                }
                const unsigned short* wp =
                    wa2f + ((size_t)(u * 2)) * 512 + l * 8;
                v8s b0 = *(const v8s*)(wp);
                v8s b1 = *(const v8s*)(wp + 512);
                acc0 = __builtin_amdgcn_mfma_f32_16x16x32_bf16(a, b0, acc0, 0, 0, 0);
                acc1 = __builtin_amdgcn_mfma_f32_16x16x32_bf16(a, b1, acc1, 0, 0, 0);
            }
        }
    }

    {                                       // publish 8 dwords/lane (scalar)
#pragma unroll
        for (int j = 0; j < 4; ++j) red1[wid][j][l] = acc0[j];
#pragma unroll
        for (int j = 0; j < 4; ++j) red1[wid][4 + j][l] = acc1[j];
    }
    __syncthreads();                        // barrier A (patchL dead)

    {   // reduce + epilogue: wave w owns output-dword slot j = w
        int j = wid;
        float v = 0.f;
#pragma unroll
        for (int sw = 0; sw < 8; ++sw) v += red1[sw][j][l];
        int r = j & 3;
        int oc = (j < 4) ? m : 16 + m;
        int pos = g * 4 + r;
        if (oc < 18) {
            lraw[pos * 28 + oc] = v + b_off[oc];
        } else if (oc < 27) {
            lraw[pos * 28 + oc] =
                2.0f / (1.0f + __expf(-(v + b_mod[oc - 18])));
        }
    }
    __syncthreads();                        // barrier B (red1 dead, red2 born)

    // ---- Phase 2: wave w owns tap w; tap 8 split by ks to waves 6/7 ----
    v4f acc[4];
#pragma unroll
    for (int nt = 0; nt < 4; ++nt) acc[nt] = (v4f){0.f, 0.f, 0.f, 0.f};

    auto do_tap = [&](int k) {
        int ky = k / 3, kx = k - 3 * ky;
        float dy = lraw[m * 28 + 2 * k];
        float dx = lraw[m * 28 + 2 * k + 1];
        float mm = lraw[m * 28 + 18 + k];

        float py = (float)(y - 1 + ky) + dy;
        float px = (float)(x - 1 + kx) + dx;
        float fy = floorf(py), fx = floorf(px);
        int   y0 = (int)fy,    x0 = (int)fx;
        float wy = py - fy,    wx = px - fx;
        int   y1 = y0 + 1,     x1 = x0 + 1;

        bool y0v = (y0 >= 0) && (y0 < HH);
        bool y1v = (y1 >= 0) && (y1 < HH);
        bool x0v = (x0 >= 0) && (x0 < WW);
        bool x1v = (x1 >= 0) && (x1 < WW);

        float w00 = (1.f - wy) * (1.f - wx) * ((y0v && x0v) ? mm : 0.f);
        float w01 = (1.f - wy) * wx         * ((y0v && x1v) ? mm : 0.f);
        float w10 = wy * (1.f - wx)         * ((y1v && x0v) ? mm : 0.f);
        float w11 = wy * wx                 * ((y1v && x1v) ? mm : 0.f);

        int y0c = min(max(y0, 0), HH - 1), y1c = min(max(y1, 0), HH - 1);
        int x0c = min(max(x0, 0), WW - 1), x1c = min(max(x1, 0), WW - 1);
        int i00 = y0c * WW + x0c, i01 = y0c * WW + x1c;
        int i10 = y1c * WW + x0c, i11 = y1c * WW + x1c;

        const uint4* p0 = xpb + (size_t)(8 + 2 * g) * HWP;
        const uint4* p1 = p0 + HWP;

        uint4 a00 = p0[i00];
        uint4 a01 = p0[i01];
        uint4 a10 = p0[i10];
        uint4 a11 = p0[i11];
        uint4 c00 = p1[i00];
        uint4 c01 = p1[i01];
        uint4 c10 = p1[i10];
        uint4 c11 = p1[i11];

        uint4 ov0, ov1;
        ov0.x = bil2(a00.x, a01.x, a10.x, a11.x, w00, w01, w10, w11);
        ov0.y = bil2(a00.y, a01.y, a10.y, a11.y, w00, w01, w10, w11);
        ov0.z = bil2(a00.z, a01.z, a10.z, a11.z, w00, w01, w10, w11);
        ov0.w = bil2(a00.w, a01.w, a10.w, a11.w, w00, w01, w10, w11);
        ov1.x = bil2(c00.x, c01.x, c10.x, c11.x, w00, w01, w10, w11);
        ov1.y = bil2(c00.y, c01.y, c10.y, c11.y, w00, w01, w10, w11);
        ov1.z = bil2(c00.z, c01.z, c10.z, c11.z, w00, w01, w10, w11);
        ov1.w = bil2(c00.w, c01.w, c10.w, c11.w, w00, w01, w10, w11);
        v8s af0 = __builtin_bit_cast(v8s, ov0);
        v8s af1 = __builtin_bit_cast(v8s, ov1);

#pragma unroll
        for (int nt = 0; nt < 4; ++nt) {
            const unsigned short* wp0 =
                wb2f + ((size_t)((k * 2 + 0) * 4 + nt)) * 512 + l * 8;
            const unsigned short* wp1 =
                wb2f + ((size_t)((k * 2 + 1) * 4 + nt)) * 512 + l * 8;
            v8s bb0 = *(const v8s*)wp0;
            v8s bb1 = *(const v8s*)wp1;
            acc[nt] = __builtin_amdgcn_mfma_f32_16x16x32_bf16(af0, bb0, acc[nt], 0, 0, 0);
            acc[nt] = __builtin_amdgcn_mfma_f32_16x16x32_bf16(af1, bb1, acc[nt], 0, 0, 0);
        }
    };

    auto do_half = [&](int k, int ks) {
        int ky = k / 3, kx = k - 3 * ky;
        float dy = lraw[m * 28 + 2 * k];
        float dx = lraw[m * 28 + 2 * k + 1];
        float mm = lraw[m * 28 + 18 + k];

        float py = (float)(y - 1 + ky) + dy;
        float px = (float)(x - 1 + kx) + dx;
        float fy = floorf(py), fx = floorf(px);
        int   y0 = (int)fy,    x0 = (int)fx;
        float wy = py - fy,    wx = px - fx;
        int   y1 = y0 + 1,     x1 = x0 + 1;

        bool y0v = (y0 >= 0) && (y0 < HH);
        bool y1v = (y1 >= 0) && (y1 < HH);
        bool x0v = (x0 >= 0) && (x0 < WW);
        bool x1v = (x1 >= 0) && (x1 < WW);

        float w00 = (1.f - wy) * (1.f - wx) * ((y0v && x0v) ? mm : 0.f);
        float w01 = (1.f - wy) * wx         * ((y0v && x1v) ? mm : 0.f);
        float w10 = wy * (1.f - wx)         * ((y1v && x0v) ? mm : 0.f);
        float w11 = wy * wx                 * ((y1v && x1v) ? mm : 0.f);

        int y0c = min(max(y0, 0), HH - 1), y1c = min(max(y1, 0), HH - 1);
        int x0c = min(max(x0, 0), WW - 1), x1c = min(max(x1, 0), WW - 1);
        int i00 = y0c * WW + x0c, i01 = y0c * WW + x1c;
        int i10 = y1c * WW + x0c, i11 = y1c * WW + x1c;

        const uint4* pk = xpb + (size_t)(8 + 2 * g + ks) * HWP;
        uint4 a00 = pk[i00];
        uint4 a01 = pk[i01];
        uint4 a10 = pk[i10];
        uint4 a11 = pk[i11];

        uint4 ov;
        ov.x = bil2(a00.x, a01.x, a10.x, a11.x, w00, w01, w10, w11);
        ov.y = bil2(a00.y, a01.y, a10.y, a11.y, w00, w01, w10, w11);
        ov.z = bil2(a00.z, a01.z, a10.z, a11.z, w00, w01, w10, w11);
        ov.w = bil2(a00.w, a01.w, a10.w, a11.w, w00, w01, w10, w11);
        v8s af = __builtin_bit_cast(v8s, ov);

#pragma unroll
        for (int nt = 0; nt < 4; ++nt) {
            const unsigned short* wp =
                wb2f + ((size_t)((k * 2 + ks) * 4 + nt)) * 512 + l * 8;
            v8s bb = *(const v8s*)wp;
            acc[nt] = __builtin_amdgcn_mfma_f32_16x16x32_bf16(af, bb, acc[nt], 0, 0, 0);
        }
    };

    do_tap(wid);
    if (wid == 6) do_half(8, 0);
    if (wid == 7) do_half(8, 1);

    // ---- Two-stage cross-wave reduction (red2 = 4 buffers, 16 KB) ----
    if (wid >= 4) {                         // stage A: waves 4-7 publish
        float* rb = red2 + ((size_t)(wid - 4) * 16) * 64;
#pragma unroll
        for (int nt = 0; nt < 4; ++nt)
#pragma unroll
            for (int r = 0; r < 4; ++r)
                rb[(nt * 4 + r) * 64 + l] = acc[nt][r];
    }
    __syncthreads();                        // barrier C1
    if (wid < 4) {                          // stage B: waves 0-3 add in place
        float* rb = red2 + ((size_t)wid * 16) * 64;
#pragma unroll
        for (int nt = 0; nt < 4; ++nt)
#pragma unroll
            for (int r = 0; r < 4; ++r) {
                float t = rb[(nt * 4 + r) * 64 + l] + acc[nt][r];
                rb[(nt * 4 + r) * 64 + l] = t;
            }
    }
    __syncthreads();                        // barrier C2
    {   // stage C: wave w reduces slots {nt*4+r0, +1} over 4 buffers
        int nt = wid >> 1, r0 = (wid & 1) * 2;
        float v0 = 0.f, v1 = 0.f;
#pragma unroll
        for (int bu = 0; bu < 4; ++bu) {
            v0 += red2[((size_t)bu * 16 + nt * 4 + r0) * 64 + l];
            v1 += red2[((size_t)bu * 16 + nt * 4 + r0 + 1) * 64 + l];
        }
        float* op = out + ((size_t)(b * COUT + nt * 16 + m)) * HW
                  + hw0 + g * 4 + r0;
        float2 s2 = {v0, v1};
        *(float2*)op = s2;
    }
}

extern "C" void kernel_launch(void* const* d_in, const int* in_sizes, int n_in,
                              void* d_out, int out_size, void* d_ws, size_t ws_size,
                              hipStream_t stream)
{
    const float* frame_i = (const float*)d_in[0];
    const float* frame_j = (const float*)d_in[1];
    const float* flow_ij = (const float*)d_in[2];
    const float* w_off   = (const float*)d_in[3];
    const float* b_off   = (const float*)d_in[4];
    const float* w_mod   = (const float*)d_in[5];
    const float* b_mod   = (const float*)d_in[6];
    const float* w_reg   = (const float*)d_in[7];
    float* out = (float*)d_out;

    // workspace: xp uint4[BB*NPL*HWP] (~10 MB) | Wa2f | Wb2f
    uint4* xp = (uint4*)d_ws;
    unsigned short* wa2f = (unsigned short*)(xp + (size_t)BB * NPL * HWP);
    unsigned short* wb2f = wa2f + NA;

    prep_kernel<<<PXB3 + PWBLK + 1, 256, 0, stream>>>(
        frame_i, frame_j, flow_ij, w_off, w_mod, w_reg, xp, wa2f, wb2f);

    fused_kernel<<<NSTRIP, 512, 0, stream>>>(
        xp, wa2f, wb2f, b_off, b_mod, out);
}